// Round 2
// baseline (1321.603 us; speedup 1.0000x reference)
//
#include <hip/hip_runtime.h>

// out[b,o] = sum_{i<64, l<32} obs[b,i,l,o] * ctx[b, 31-l, i]
// B=2048, R=32, O=64, fp32. HBM-bound: obs = 1 GiB streamed once (floor ~171 us).

#define BB 2048
#define RR 32
#define OO 64

__global__ __launch_bounds__(256) void cnnkf_kernel(
    const float* __restrict__ ctx,   // [B, R, O]
    const float* __restrict__ obs,   // [B, O, R, O]
    float* __restrict__ out)         // [B, O]
{
    __shared__ float  lds_tmp[RR * OO];   // 8 KB: ctx[b] staged coalesced; reused for reduction
    __shared__ float4 ldsF4[16 * 33];     // 8.25 KB: flipped-transposed c table, padded [s][33]

    const int b  = blockIdx.x;
    const int t  = threadIdx.x;
    const int og = t & 15;   // float4 group along o
    const int s  = t >> 4;   // slice 0..15 over the 2048 (i,l) pairs

    // Stage ctx[b] (32x64 floats) into LDS, coalesced float4.
    const float4* ctx4 = reinterpret_cast<const float4*>(ctx + (size_t)b * (RR * OO));
    float4* tmp4 = reinterpret_cast<float4*>(lds_tmp);
    tmp4[t]       = ctx4[t];
    tmp4[t + 256] = ctx4[t + 256];
    __syncthreads();

    // Build c table: c(p) = ctx[b, 31-(p&31), p>>5] for p = i*32+l in [0,2048).
    // Stored as float4 groups: ldsF4[s*33 + g] = { c(s*128+4g+m) : m=0..3 }.
    // Pad 33 makes the 4 per-wave s-slices land on distinct banks (conflict-free b128 reads).
    #pragma unroll
    for (int j = 0; j < 2; ++j) {
        const int q  = 2 * t + j;        // c-group index 0..511
        const int sq = q >> 5;
        const int gq = q & 31;
        const int p0 = 4 * q;
        const int i  = p0 >> 5;          // constant across the 4-group (4 | 32)
        const int l0 = p0 & 31;
        float4 c;
        c.x = lds_tmp[(31 - (l0 + 0)) * OO + i];
        c.y = lds_tmp[(31 - (l0 + 1)) * OO + i];
        c.z = lds_tmp[(31 - (l0 + 2)) * OO + i];
        c.w = lds_tmp[(31 - (l0 + 3)) * OO + i];
        ldsF4[sq * 33 + gq] = c;
    }
    __syncthreads();

    // Main stream: thread covers p in [s*128, s*128+128), o = 4*og..4*og+3.
    // obs float4 index = p*16 + og; group g of 4 k's -> offsets 0,16,32,48, then +64.
    const float4* obs4 = reinterpret_cast<const float4*>(obs + (size_t)b * (OO * RR * OO));
    const float4* op = obs4 + (size_t)(s * 128) * 16 + og;
    const float4* cp = &ldsF4[s * 33];

    float4 acc = {0.f, 0.f, 0.f, 0.f};
    #pragma unroll 4
    for (int g = 0; g < 32; ++g) {
        const float4 c  = cp[g];          // one ds_read_b128 per 4 k, conflict-free
        const float4 v0 = op[0];
        const float4 v1 = op[16];
        const float4 v2 = op[32];
        const float4 v3 = op[48];
        op += 64;
        acc.x += v0.x * c.x; acc.y += v0.y * c.x; acc.z += v0.z * c.x; acc.w += v0.w * c.x;
        acc.x += v1.x * c.y; acc.y += v1.y * c.y; acc.z += v1.z * c.y; acc.w += v1.w * c.y;
        acc.x += v2.x * c.z; acc.y += v2.y * c.z; acc.z += v2.z * c.z; acc.w += v2.w * c.z;
        acc.x += v3.x * c.w; acc.y += v3.y * c.w; acc.z += v3.z * c.w; acc.w += v3.w * c.w;
    }

    // Tree-reduce the 16 slices (reuse lds_tmp; stride multiple of 16 keeps og aligned).
    __syncthreads();
    float4* red = reinterpret_cast<float4*>(lds_tmp);
    red[t] = acc;
    __syncthreads();
    for (int stride = 128; stride >= 16; stride >>= 1) {
        if (t < stride) {
            float4 a = red[t];
            const float4 c2 = red[t + stride];
            a.x += c2.x; a.y += c2.y; a.z += c2.z; a.w += c2.w;
            red[t] = a;
        }
        __syncthreads();
    }

    if (t < 16) {
        reinterpret_cast<float4*>(out + (size_t)b * OO)[t] = red[t];
    }
}

extern "C" void kernel_launch(void* const* d_in, const int* in_sizes, int n_in,
                              void* d_out, int out_size, void* d_ws, size_t ws_size,
                              hipStream_t stream) {
    const float* ctx = (const float*)d_in[0];  // context [2048, 32, 64]
    const float* obs = (const float*)d_in[1];  // observation_IR [2048, 64, 32, 64]
    float* out = (float*)d_out;                // [2048, 64]
    cnnkf_kernel<<<dim3(BB), dim3(256), 0, stream>>>(ctx, obs, out);
}